// Round 3
// baseline (108.564 us; speedup 1.0000x reference)
//
#include <hip/hip_runtime.h>

// HistoLoss: B=1024, T=256, C=16, NB=64; TC=4096; x flat = [b][tc]
//
// R16: MEASUREMENT ROUND. R15 (pk-u16 inner loop, 1.5x fewer VALU inst)
// came back exactly flat vs R12 (90.31 vs 90.26) => inner-loop issue is
// NOT the critical path, or k1 is much smaller than the inherited 25us
// estimate. k1's duration has never been directly observed this session
// (rocprof top-5 = poison fills only). This round launches k1 TWICE:
//   dur - 90.3 = k1 + ~2us launch gap.
// Safe: counts deterministic (2nd launch rewrites identical bytes);
// out[0] re-zeroed by k1 block 0 before k2; stream-ordered. absmax 0.0
// preserved.
//   H1 (k1~25us, not issue-bound)  -> dur ~115us -> structural k1 rewrite
//   H2 (k1~10-12us, journal stale) -> dur ~103us -> at harness floor
//
// k1: 256 thr = 2 b-subgroups x (16 c x 8 kq); block = (t, 128-b chunk);
//     grid 2048. LDS rows xsp[c][68] u32 (u16-pair fixed-point, x*4096).
//     Inner: 4 VOP3P per 2 indicators (pk_sub / pk_sub-clamp / pk_min /
//     pk_add), bit-exact vs R12 predicate (16-bit modular wrap safe:
//     |xq-qlo| <= ~35K < 65536-qw).
// k2: sum 16 chunk u8s, loss, block-reduce, one atomicAdd/block.

#define T_DIM   256
#define C_DIM   16
#define NB      64
#define TC      4096
#define CHUNKS  16
#define BBLK    128
#define KPT     8
#define PITCH   68             // xsp row pitch in u32 (64 pairs + 4 pad)
#define QSCALE  4096.0f        // fixed-point scale (|xq| < 2^15)

__global__ __launch_bounds__(256, 8) void histo_count_kernel(
    const float* __restrict__ x,       // [1024, 4096]
    const float* __restrict__ locs,    // [4096, 64]
    const float* __restrict__ deltas,  // [4096]
    unsigned char* __restrict__ counts,// [CHUNKS][4096][64] u8
    float* __restrict__ out)           // [1] (zeroed for k2's atomics)
{
    __shared__ int xsp[C_DIM * PITCH];           // 16 x 68 u32 = 4352 B
    const int tid   = threadIdx.x;
    const int t     = blockIdx.x & 255;
    const int chunk = blockIdx.x >> 8;           // 0..7 (128 b each)

    if (blockIdx.x == 0 && tid == 0) out[0] = 0.0f;

    // Stage x[chunk*128 .. +127][t*16 .. +15] -> u16-pair fixed-point.
    // Row b0 (even) -> lo16, row b0+1 (odd) -> hi16.
    {
        const int bpair = tid >> 2;              // 0..63
        const int c4    = (tid & 3) * 4;
        const int b0    = 2 * bpair;
        const float* r0 = x + (size_t)(chunk * BBLK + b0) * TC + t * C_DIM + c4;
        const float4 va = *(const float4*)r0;
        const float4 vb = *(const float4*)(r0 + TC);
        const float a[4] = {va.x, va.y, va.z, va.w};
        const float b[4] = {vb.x, vb.y, vb.z, vb.w};
#pragma unroll
        for (int k = 0; k < 4; ++k) {
            const int pa = __float2int_rn(a[k] * QSCALE);
            const int pb = __float2int_rn(b[k] * QSCALE);
            xsp[(c4 + k) * PITCH + bpair] = (pa & 0xFFFF) | (pb << 16);
        }
    }

    const int bg = tid >> 7;           // b-subgroup: 64 b's = 32 pairs each
    const int r  = tid & 127;
    const int c  = r >> 3;             // 0..15
    const int kq = r & 7;              // bins [kq*8, kq*8+8)
    const int tc = t * C_DIM + c;

    const float hf = 0.5f * deltas[tc];
    const int   qw = __float2int_rn(2.0f * hf * QSCALE);   // window width
    const int   w2 = (qw & 0xFFFF) | (qw << 16);           // replicated
    const int  one2 = 0x00010001;

    int lo2[KPT];                       // window low edge, replicated u16x2
    const float* lp = locs + (size_t)tc * NB + kq * KPT;
#pragma unroll
    for (int j = 0; j < KPT; ++j) {
        const int q = __float2int_rn((lp[j] - hf) * QSCALE);
        lo2[j] = (q & 0xFFFF) | (q << 16);
    }

    int acc[KPT];                       // u16x2: even-b count | odd-b count
#pragma unroll
    for (int j = 0; j < KPT; ++j) acc[j] = 0;

    __syncthreads();

    // 8 iters x (1 ds_read_b128 = 8 x's as 4 u16-pairs) x 8 bins x
    // 4 VOP3P per (pair, bin) = 2 inst/indicator.
    const int4* xr = (const int4*)(xsp + c * PITCH + bg * 32);
#pragma unroll 4
    for (int g = 0; g < 8; ++g) {
        const int4 u = xr[g];
        const int xx[4] = {u.x, u.y, u.z, u.w};
#pragma unroll
        for (int q = 0; q < 4; ++q) {
#pragma unroll
            for (int j = 0; j < KPT; ++j) {
                int tmp;
                asm("v_pk_sub_u16 %0, %2, %3\n\t"
                    "v_pk_sub_u16 %0, %4, %0 clamp\n\t"
                    "v_pk_min_u16 %0, %0, %5\n\t"
                    "v_pk_add_u16 %1, %1, %0"
                    : "=&v"(tmp), "+v"(acc[j])
                    : "v"(xx[q]), "v"(lo2[j]), "v"(w2), "v"(one2));
            }
        }
    }

    unsigned long long pack = 0;
#pragma unroll
    for (int j = 0; j < KPT; ++j) {
        const unsigned s = ((unsigned)acc[j] + ((unsigned)acc[j] >> 16)) & 0xFFu;
        pack |= (unsigned long long)s << (8 * j);          // <=64 each
    }
    *(unsigned long long*)(counts + (size_t)(chunk * 2 + bg) * (TC * NB)
                                  + (size_t)tc * NB + kq * KPT) = pack;
}

__global__ __launch_bounds__(256) void histo_loss_kernel(
    const unsigned char* __restrict__ counts, // [CHUNKS][4096][64]
    const float* __restrict__ deltas,         // [4096]
    const float* __restrict__ dens,           // [4096, 64]
    float* __restrict__ out)                  // [1]
{
    const int gid = blockIdx.x * 256 + threadIdx.x;
    const int i0  = gid * 4;                  // 4 consecutive items, same tc

    int cnt[4] = {0, 0, 0, 0};
#pragma unroll
    for (int ch = 0; ch < CHUNKS; ++ch) {
        const unsigned u = *(const unsigned*)(counts + (size_t)ch * (TC * NB) + i0);
#pragma unroll
        for (int q = 0; q < 4; ++q)
            cnt[q] += (int)((u >> (8 * q)) & 0xffu);
    }

    const float delta = deltas[i0 >> 6];
    const float4 dv = *(const float4*)(dens + i0);
    // Reference order: (cnt/1024) exact, then / delta.
    float s = fabsf((cnt[0] * (1.0f / 1024.0f)) / delta - dv.x)
            + fabsf((cnt[1] * (1.0f / 1024.0f)) / delta - dv.y)
            + fabsf((cnt[2] * (1.0f / 1024.0f)) / delta - dv.z)
            + fabsf((cnt[3] * (1.0f / 1024.0f)) / delta - dv.w);

#pragma unroll
    for (int off = 32; off > 0; off >>= 1)
        s += __shfl_down(s, off, 64);

    __shared__ float sb[4];
    if ((threadIdx.x & 63) == 0) sb[threadIdx.x >> 6] = s;
    __syncthreads();

    if (threadIdx.x == 0)   // REG * mean over (t,c,k) = sum / 262144
        atomicAdd(out, (sb[0] + sb[1] + sb[2] + sb[3]) * (1.0f / 262144.0f));
}

extern "C" void kernel_launch(void* const* d_in, const int* in_sizes, int n_in,
                              void* d_out, int out_size, void* d_ws, size_t ws_size,
                              hipStream_t stream) {
    const float* x      = (const float*)d_in[0];  // x_fake    [1024,256,16]
    const float* locs   = (const float*)d_in[1];  // locs      [256,16,64]
    const float* deltas = (const float*)d_in[2];  // deltas    [256,16]
    const float* dens   = (const float*)d_in[3];  // densities [256,16,64]
    float* out = (float*)d_out;
    unsigned char* cnts = (unsigned char*)d_ws;   // 4 MB scratch

    // MEASUREMENT: k1 launched twice (idempotent). dur - 90.3 = k1 + gap.
    histo_count_kernel<<<T_DIM * 8, 256, 0, stream>>>(x, locs, deltas, cnts, out);
    histo_count_kernel<<<T_DIM * 8, 256, 0, stream>>>(x, locs, deltas, cnts, out);
    histo_loss_kernel<<<(TC * NB) / (256 * 4), 256, 0, stream>>>(cnts, deltas, dens, out);
}

// Round 4
// 89.621 us; speedup vs baseline: 1.2114x; 1.2114x over previous
//
#include <hip/hip_runtime.h>

// HistoLoss: B=1024, T=256, C=16, NB=64; TC=4096; x flat = [b][tc]
//
// R16 measurement: k1 = 18.25us directly (double-launch delta). With R15
// (pk-u16, 1.5x fewer inner inst) flat vs R12 => k1 NOT inner-issue-bound
// (issue floor ~6.8us); ~11us is stage-latency/barrier/tail. Journal's
// "25us, 3cyc/inst ceiling" was stale.
//
// R17 (this round): pipeline the phases. Grid 2048->4096: block = (t,
// 64-b chunk), 2 rounds of 8 resident blocks/CU, so round-2 staging
// overlaps round-1 compute and the tail halves. Same total pk work;
// kq widened to 16 threads (KPT=4 bins each, 64 b's). Slices stay 16
// (chunk-only; per-thread sub-counts <=32/half, sum <=64, u8 ok) so k2
// is byte-identical. Predict k1 18.25 -> ~14us, total ~86us; if flat,
// the residue is per-dispatch overhead => roofline arithmetic next.
//
// k1: 256 thr = 16 c x 16 kq; stage by 128 thr (f32->u16-pair fixed
//     point, x*4096; bit-exact predicate: |xq-qlo| <= ~35K < 65536-qw so
//     16-bit modular wrap preserves unsigned <). LDS xsp[c][36] u32
//     (32 pairs + 4 pad): reads 16-way broadcast, disjoint 4-bank spans
//     per c (conflict-free); staging writes 2-way (free, m136).
//     Inner: 8 x ds_read_b128 x 4 q x 4 j x 4 VOP3P = 2 inst/indicator.
// k2: sum 16 chunk u8s, loss, block-reduce, one atomicAdd/block (out[0]
//     zeroed by k1 block 0; stream-ordered).

#define T_DIM   256
#define C_DIM   16
#define NB      64
#define TC      4096
#define CHUNKS  16
#define BBLK    64             // b-rows per block (was 128)
#define KPT     4              // bins per thread (was 8)
#define PITCH   36             // xsp row pitch in u32 (32 pairs + 4 pad)
#define QSCALE  4096.0f        // fixed-point scale (|xq| < 2^15)

__global__ __launch_bounds__(256, 8) void histo_count_kernel(
    const float* __restrict__ x,       // [1024, 4096]
    const float* __restrict__ locs,    // [4096, 64]
    const float* __restrict__ deltas,  // [4096]
    unsigned char* __restrict__ counts,// [CHUNKS][4096][64] u8
    float* __restrict__ out)           // [1] (zeroed for k2's atomics)
{
    __shared__ int xsp[C_DIM * PITCH];           // 16 x 36 u32 = 2304 B
    const int tid   = threadIdx.x;
    const int t     = blockIdx.x & 255;
    const int chunk = blockIdx.x >> 8;           // 0..15 (64 b each)

    if (blockIdx.x == 0 && tid == 0) out[0] = 0.0f;

    // Stage x[chunk*64 .. +63][t*16 .. +15] -> u16-pair fixed-point.
    // 128 threads: row b0 (even) -> lo16, row b0+1 (odd) -> hi16.
    if (tid < 128) {
        const int bpair = tid >> 2;              // 0..31
        const int c4    = (tid & 3) * 4;
        const int b0    = 2 * bpair;
        const float* r0 = x + (size_t)(chunk * BBLK + b0) * TC + t * C_DIM + c4;
        const float4 va = *(const float4*)r0;
        const float4 vb = *(const float4*)(r0 + TC);
        const float a[4] = {va.x, va.y, va.z, va.w};
        const float b[4] = {vb.x, vb.y, vb.z, vb.w};
#pragma unroll
        for (int k = 0; k < 4; ++k) {
            const int pa = __float2int_rn(a[k] * QSCALE);
            const int pb = __float2int_rn(b[k] * QSCALE);
            xsp[(c4 + k) * PITCH + bpair] = (pa & 0xFFFF) | (pb << 16);
        }
    }

    const int kq = tid & 15;           // bins [kq*4, kq*4+4)
    const int c  = tid >> 4;           // 0..15
    const int tc = t * C_DIM + c;

    const float hf = 0.5f * deltas[tc];
    const int   qw = __float2int_rn(2.0f * hf * QSCALE);   // window width
    const int   w2 = (qw & 0xFFFF) | (qw << 16);           // replicated
    const int  one2 = 0x00010001;

    int lo2[KPT];                       // window low edge, replicated u16x2
    const float4 lv = *(const float4*)(locs + (size_t)tc * NB + kq * KPT);
    const float lf[4] = {lv.x, lv.y, lv.z, lv.w};
#pragma unroll
    for (int j = 0; j < KPT; ++j) {
        const int q = __float2int_rn((lf[j] - hf) * QSCALE);
        lo2[j] = (q & 0xFFFF) | (q << 16);
    }

    int acc[KPT];                       // u16x2: even-b count | odd-b count
#pragma unroll
    for (int j = 0; j < KPT; ++j) acc[j] = 0;

    __syncthreads();

    // 8 iters x (1 ds_read_b128 = 8 x's as 4 u16-pairs) x 4 pairs x
    // 4 bins x 4 VOP3P = 2 inst/indicator. 512 pk-inst/thread.
    const int4* xr = (const int4*)(xsp + c * PITCH);
#pragma unroll 4
    for (int g = 0; g < 8; ++g) {
        const int4 u = xr[g];
        const int xx[4] = {u.x, u.y, u.z, u.w};
#pragma unroll
        for (int q = 0; q < 4; ++q) {
#pragma unroll
            for (int j = 0; j < KPT; ++j) {
                int tmp;
                asm("v_pk_sub_u16 %0, %2, %3\n\t"
                    "v_pk_sub_u16 %0, %4, %0 clamp\n\t"
                    "v_pk_min_u16 %0, %0, %5\n\t"
                    "v_pk_add_u16 %1, %1, %0"
                    : "=&v"(tmp), "+v"(acc[j])
                    : "v"(xx[q]), "v"(lo2[j]), "v"(w2), "v"(one2));
            }
        }
    }

    unsigned pack = 0;
#pragma unroll
    for (int j = 0; j < KPT; ++j) {
        const unsigned s = ((unsigned)acc[j] + ((unsigned)acc[j] >> 16)) & 0xFFu;
        pack |= s << (8 * j);                              // <=64 each
    }
    *(unsigned*)(counts + (size_t)chunk * (TC * NB)
                        + (size_t)tc * NB + kq * KPT) = pack;
}

__global__ __launch_bounds__(256) void histo_loss_kernel(
    const unsigned char* __restrict__ counts, // [CHUNKS][4096][64]
    const float* __restrict__ deltas,         // [4096]
    const float* __restrict__ dens,           // [4096, 64]
    float* __restrict__ out)                  // [1]
{
    const int gid = blockIdx.x * 256 + threadIdx.x;
    const int i0  = gid * 4;                  // 4 consecutive items, same tc

    int cnt[4] = {0, 0, 0, 0};
#pragma unroll
    for (int ch = 0; ch < CHUNKS; ++ch) {
        const unsigned u = *(const unsigned*)(counts + (size_t)ch * (TC * NB) + i0);
#pragma unroll
        for (int q = 0; q < 4; ++q)
            cnt[q] += (int)((u >> (8 * q)) & 0xffu);
    }

    const float delta = deltas[i0 >> 6];
    const float4 dv = *(const float4*)(dens + i0);
    // Reference order: (cnt/1024) exact, then / delta.
    float s = fabsf((cnt[0] * (1.0f / 1024.0f)) / delta - dv.x)
            + fabsf((cnt[1] * (1.0f / 1024.0f)) / delta - dv.y)
            + fabsf((cnt[2] * (1.0f / 1024.0f)) / delta - dv.z)
            + fabsf((cnt[3] * (1.0f / 1024.0f)) / delta - dv.w);

#pragma unroll
    for (int off = 32; off > 0; off >>= 1)
        s += __shfl_down(s, off, 64);

    __shared__ float sb[4];
    if ((threadIdx.x & 63) == 0) sb[threadIdx.x >> 6] = s;
    __syncthreads();

    if (threadIdx.x == 0)   // REG * mean over (t,c,k) = sum / 262144
        atomicAdd(out, (sb[0] + sb[1] + sb[2] + sb[3]) * (1.0f / 262144.0f));
}

extern "C" void kernel_launch(void* const* d_in, const int* in_sizes, int n_in,
                              void* d_out, int out_size, void* d_ws, size_t ws_size,
                              hipStream_t stream) {
    const float* x      = (const float*)d_in[0];  // x_fake    [1024,256,16]
    const float* locs   = (const float*)d_in[1];  // locs      [256,16,64]
    const float* deltas = (const float*)d_in[2];  // deltas    [256,16]
    const float* dens   = (const float*)d_in[3];  // densities [256,16,64]
    float* out = (float*)d_out;
    unsigned char* cnts = (unsigned char*)d_ws;   // 4 MB scratch

    histo_count_kernel<<<T_DIM * CHUNKS, 256, 0, stream>>>(x, locs, deltas, cnts, out);
    histo_loss_kernel<<<(TC * NB) / (256 * 4), 256, 0, stream>>>(cnts, deltas, dens, out);
}